// Round 4
// baseline (347.847 us; speedup 1.0000x reference)
//
#include <hip/hip_runtime.h>

// Problem constants (fixed by the reference: x,y are (3000, 800, 8) f32)
#define NT   3000          // time samples per trace
#define NK   2999          // NT-1 (cdf length)
#define NTR  6400          // traces (800*8); trace n element t at X[t*NTR+n]
#define NPAIR 3200         // NTR/2 (float2 trace pairs)
#define CCH  64            // time chunks per trace
#define KCH  47            // ceil(NK/CCH); last chunk has 38
#define GRP  8             // obs register-group size
#define GT   64            // traces per kB block

// sum_{i=1..2999} i (weight for folding mind into S = sum of cdf)
#define TRIW 4498500.0f
#define FINF 3.4e38f

// ---------------------------------------------------------------------------
// Kernel A: per (trace-pair p, chunk c), float2-vectorized chunk stats.
// Chunk sums -> offx/offy (kB scans in-place); chunk min -> cmn; weighted
// sums s_raw*(NK-j) atomically folded into wsxA/wsyA (pre-zeroed).
// ---------------------------------------------------------------------------
__global__ __launch_bounds__(128) void kA(
    const float* __restrict__ X, const float* __restrict__ Y,
    float* __restrict__ offx, float* __restrict__ offy,
    float* __restrict__ cmn,
    float* __restrict__ wsxA, float* __restrict__ wsyA)
{
    const int p = blockIdx.x * 128 + threadIdx.x;   // pair index 0..3199
    const int n = 2 * p;
    const int c = blockIdx.y;
    const int j0 = c * KCH;
    const int j1 = min(NK, j0 + KCH);

    const float2* __restrict__ X2 = (const float2*)X;
    const float2* __restrict__ Y2 = (const float2*)Y;

    float2 xp = X2[j0 * NPAIR + p];
    float2 yp = Y2[j0 * NPAIR + p];
    float mn0 = fminf(xp.x, yp.x), mn1 = fminf(xp.y, yp.y);
    float sx0 = 0.f, sx1 = 0.f, sy0 = 0.f, sy1 = 0.f;
    float wx0 = 0.f, wx1 = 0.f, wy0 = 0.f, wy1 = 0.f;

    #pragma unroll 8
    for (int j = j0; j < j1; ++j) {
        const float2 xn = X2[(j + 1) * NPAIR + p];
        const float2 yn = Y2[(j + 1) * NPAIR + p];
        const float w = (float)(NK - j);
        float s;
        s = 0.5f * (xp.x + xn.x); sx0 += s; wx0 = fmaf(s, w, wx0);
        s = 0.5f * (xp.y + xn.y); sx1 += s; wx1 = fmaf(s, w, wx1);
        s = 0.5f * (yp.x + yn.x); sy0 += s; wy0 = fmaf(s, w, wy0);
        s = 0.5f * (yp.y + yn.y); sy1 += s; wy1 = fmaf(s, w, wy1);
        mn0 = fminf(mn0, fminf(xn.x, yn.x));
        mn1 = fminf(mn1, fminf(xn.y, yn.y));
        xp = xn; yp = yn;
    }

    const int o = c * NTR + n;
    *(float2*)&offx[o] = make_float2(sx0, sx1);
    *(float2*)&offy[o] = make_float2(sy0, sy1);
    *(float2*)&cmn[o]  = make_float2(mn0, mn1);
    atomicAdd(&wsxA[n], wx0); atomicAdd(&wsxA[n + 1], wx1);
    atomicAdd(&wsyA[n], wy0); atomicAdd(&wsyA[n + 1], wy1);
}

// ---------------------------------------------------------------------------
// Kernel B (coalesced LDS version): 100 blocks x 256 threads, 64 traces/block.
// Stages chunk arrays via LDS (padded [64][65] tiles), does min-reduce and
// in-place exclusive scans, and precomputes ccA[c][n] = conservative obs
// start chunk for every syn chunk via a two-pointer boundary merge.
// ---------------------------------------------------------------------------
__global__ __launch_bounds__(256) void kB(
    float* __restrict__ offx, float* __restrict__ offy,
    const float* __restrict__ cmn,
    const float* __restrict__ wsxA, const float* __restrict__ wsyA,
    float* __restrict__ mindA, float* __restrict__ SsynA,
    float* __restrict__ SobsA, unsigned char* __restrict__ ccA,
    float* __restrict__ out)
{
    __shared__ float tA[CCH][GT + 1];
    __shared__ float tB[CCH][GT + 1];
    __shared__ float mindS[GT], SsS[GT], SoS[GT];

    const int n0 = blockIdx.x * GT;
    const int tid = threadIdx.x;
    const int lane = tid & 63;
    const int crow = tid >> 6;                      // 0..3
    if (blockIdx.x == 0 && tid == 0) out[0] = 0.0f;

    // stage cmn -> tB (coalesced), per-trace min reduce
    for (int c = crow; c < CCH; c += 4)
        tB[c][lane] = cmn[c * NTR + n0 + lane];
    __syncthreads();
    if (tid < GT) {
        float mn = FINF;
        for (int c = 0; c < CCH; ++c) mn = fminf(mn, tB[c][tid]);
        mindS[tid] = mn;
        mindA[n0 + tid] = mn;
        const float ss = wsxA[n0 + tid] - mn * TRIW;
        const float so = wsyA[n0 + tid] - mn * TRIW;
        SsS[tid] = ss; SoS[tid] = so;
        SsynA[n0 + tid] = ss;
        SobsA[n0 + tid] = so;
    }
    __syncthreads();

    // stage chunk sums, exclusive-scan in LDS
    for (int c = crow; c < CCH; c += 4) {
        tA[c][lane] = offx[c * NTR + n0 + lane];
        tB[c][lane] = offy[c * NTR + n0 + lane];
    }
    __syncthreads();
    if (tid < GT) {
        float rx = 0.f, ry = 0.f;
        for (int c = 0; c < CCH; ++c) {
            const float tx = tA[c][tid], ty = tB[c][tid];
            tA[c][tid] = rx; tB[c][tid] = ry;
            rx += tx; ry += ty;
        }
    }
    __syncthreads();

    // write back scanned offsets (coalesced)
    for (int c = crow; c < CCH; c += 4) {
        offx[c * NTR + n0 + lane] = tA[c][lane];
        offy[c * NTR + n0 + lane] = tB[c][lane];
    }

    // obs start chunk per syn chunk: largest q with obs_bnd'(q) < syn_excl'(c)
    // (conservative lower bound for kC's first target at that chunk)
    if (tid < GT) {
        const float mind = mindS[tid], Ss = SsS[tid], So = SoS[tid];
        int q = 0;
        ccA[n0 + tid] = 0;                          // c = 0
        for (int c = 1; c < CCH; ++c) {
            const float tgt = (tA[c][tid] - (float)(c * KCH) * mind) * So;
            while (q + 1 < CCH) {
                const float ov = (tB[q + 1][tid] - (float)((q + 1) * KCH) * mind) * Ss;
                if (ov < tgt) ++q; else break;
            }
            ccA[c * NTR + n0 + tid] = (unsigned char)q;
        }
    }
}

// ---------------------------------------------------------------------------
// Kernel C: merge with register-group obs batching. XCD-grouped block
// swizzle: XCD g handles (ntile, c in [g*8, g*8+8)) back-to-back, so the
// over-walk rows of chunk c are chunk c-1's rows -> same-XCD L2 hits.
// ---------------------------------------------------------------------------
__global__ __launch_bounds__(256) void kC(
    const float* __restrict__ X, const float* __restrict__ Y,
    const float* __restrict__ offx, const float* __restrict__ offy,
    const float* __restrict__ mindA, const float* __restrict__ SsynA,
    const float* __restrict__ SobsA, const unsigned char* __restrict__ ccA,
    float* __restrict__ out)
{
    const int bid = blockIdx.x;                 // 0..1599
    const int g = bid & 7, r = bid >> 3;        // r: 0..199
    const int ntile = r >> 3;                   // 0..24
    const int c = (g << 3) | (r & 7);           // 0..63
    const int n = ntile * 256 + threadIdx.x;
    const int j0 = c * KCH;
    const int j1 = min(NK, j0 + KCH);

    const float mind = mindA[n];
    const float Ssyn = SsynA[n];
    const float Sobs = SobsA[n];
    const float invS = 1.0f / Ssyn;

    float cs = offx[c * NTR + n];               // raw syn cumsum through j0-1
    float xp = X[j0 * NTR + n];
    float acc = 0.f;

    // obs group init from precomputed start chunk
    int   mbase;
    float co, ylast;
    float o[GRP];
    float co8, y8;

    {
        const int cc = (int)ccA[c * NTR + n];
        mbase = cc * KCH;
        co    = offy[cc * NTR + n];
        ylast = Y[mbase * NTR + n];
    }

    #define FILL() do {                                                   \
        float yl_ = ylast, cc_ = co;                                      \
        _Pragma("unroll")                                                 \
        for (int i = 0; i < GRP; ++i) {                                   \
            const int m_ = mbase + i;                                     \
            const int ml_ = (m_ < NK) ? (m_ + 1) : NK;                    \
            const float yn_ = Y[ml_ * NTR + n];                           \
            cc_ += 0.5f * (yl_ + yn_);                                    \
            yl_ = yn_;                                                    \
            const float v_ = (cc_ - (float)(m_ + 1) * mind) * Ssyn;       \
            o[i] = (m_ < NK) ? v_ : FINF;                                 \
        }                                                                 \
        co8 = cc_; y8 = yl_;                                              \
    } while (0)

    #define COUNT(tgt, cnt) do {                                          \
        cnt = 0;                                                          \
        _Pragma("unroll")                                                 \
        for (int i = 0; i < GRP; ++i) cnt += (o[i] < (tgt)) ? 1 : 0;      \
    } while (0)

    FILL();

    for (int k = j0; k < j1; ++k) {
        const float xn = X[(k + 1) * NTR + n];
        cs += 0.5f * (xp + xn); xp = xn;
        const float synp = cs - (float)(k + 1) * mind;
        const float target = synp * Sobs;

        int cnt; COUNT(target, cnt);
        while (cnt == GRP) {
            mbase += GRP; co = co8; ylast = y8;
            FILL();
            COUNT(target, cnt);
        }
        const float diff = (float)(k + 1 - (mbase + cnt));
        acc = fmaf(diff * diff, synp, acc);     // invS hoisted out
    }
    acc *= invS;

    #undef FILL
    #undef COUNT

    __shared__ float red[256];
    red[threadIdx.x] = acc;
    __syncthreads();
    for (int s = 128; s > 0; s >>= 1) {
        if (threadIdx.x < s) red[threadIdx.x] += red[threadIdx.x + s];
        __syncthreads();
    }
    if (threadIdx.x == 0) atomicAdd(out, red[0]);
}

// ---------------------------------------------------------------------------
extern "C" void kernel_launch(void* const* d_in, const int* in_sizes, int n_in,
                              void* d_out, int out_size, void* d_ws, size_t ws_size,
                              hipStream_t stream)
{
    const float* X = (const float*)d_in[0];
    const float* Y = (const float*)d_in[1];
    float* out = (float*)d_out;

    float* w = (float*)d_ws;
    float* offx  = w;                    // CCH*NTR
    float* offy  = offx + CCH * NTR;     // CCH*NTR
    float* cmn   = offy + CCH * NTR;     // CCH*NTR
    float* wsxA  = cmn  + CCH * NTR;     // NTR
    float* wsyA  = wsxA + NTR;           // NTR
    float* mindA = wsyA + NTR;           // NTR
    float* SsynA = mindA + NTR;          // NTR
    float* SobsA = SsynA + NTR;          // NTR
    unsigned char* ccA = (unsigned char*)(SobsA + NTR);  // CCH*NTR bytes
    // total: 3*CCH*NTR*4 + 5*NTR*4 + CCH*NTR = 5,452,800 bytes

    hipMemsetAsync(wsxA, 0, 2 * NTR * sizeof(float), stream);

    dim3 gA(NPAIR / 128, CCH), bA(128);
    dim3 gB(NTR / GT), bB(256);
    dim3 gC(1600), bC(256);

    kA<<<gA, bA, 0, stream>>>(X, Y, offx, offy, cmn, wsxA, wsyA);
    kB<<<gB, bB, 0, stream>>>(offx, offy, cmn, wsxA, wsyA,
                              mindA, SsynA, SobsA, ccA, out);
    kC<<<gC, bC, 0, stream>>>(X, Y, offx, offy, mindA, SsynA, SobsA, ccA, out);
}